// Round 1
// baseline (224.161 us; speedup 1.0000x reference)
//
#include <hip/hip_runtime.h>
#include <cfloat>
#include <climits>

#define EOS_ID 1
#define NEXT_LINE_ID 2
#define IGNORE_IDX 0

constexpr int THREADS = 256;

// ---------------------------------------------------------------------------
// Kernel 1: one block per (b,s) row of V logits.
// Computes online softmax stats (max m, sum s of exp(x-m)), argmax with
// first-index tie-break, gathers x[target], writes nll (0 if ignored) and
// argmax index to workspace. Fully deterministic (fixed reduction order).
// ---------------------------------------------------------------------------
__global__ __launch_bounds__(THREADS) void row_pass_kernel(
    const float* __restrict__ pred, const int* __restrict__ target,
    float* __restrict__ nll_out, int* __restrict__ am_out, int V)
{
    const int row = blockIdx.x;
    const float* rp = pred + (size_t)row * (size_t)V;
    const int tid = threadIdx.x;
    const int V4 = V >> 2;

    float m = -FLT_MAX;
    float s = 0.0f;
    int bi = 0;

    const float4* rp4 = (const float4*)rp;
    for (int i = tid; i < V4; i += THREADS) {
        float4 v = rp4[i];
        float xs[4] = {v.x, v.y, v.z, v.w};
        const int base = i << 2;
#pragma unroll
        for (int c = 0; c < 4; ++c) {
            float x = xs[c];
            float nm = fmaxf(m, x);
            // branchless online softmax: when nm==m this is s*1 + exp(x-m)
            s = s * __expf(m - nm) + __expf(x - nm);
            if (x > m) bi = base + c;   // strict > keeps earliest index in-thread
            m = nm;
        }
    }
    // scalar tail (V not multiple of 4) — not hit for V=32000, kept for safety
    for (int i = (V4 << 2) + tid; i < V; i += THREADS) {
        float x = rp[i];
        float nm = fmaxf(m, x);
        s = s * __expf(m - nm) + __expf(x - nm);
        if (x > m) bi = i;
        m = nm;
    }

    // wave64 reduction
#pragma unroll
    for (int off = 32; off > 0; off >>= 1) {
        float m2 = __shfl_down(m, off);
        float s2 = __shfl_down(s, off);
        int bi2 = __shfl_down(bi, off);
        bool take = (m2 > m) || (m2 == m && bi2 < bi); // first-index tie-break
        float nm = fmaxf(m, m2);
        s = s * __expf(m - nm) + s2 * __expf(m2 - nm);
        if (take) bi = bi2;
        m = nm;
    }

    __shared__ float sm[THREADS / 64], ss[THREADS / 64];
    __shared__ int sbi[THREADS / 64];
    const int wave = tid >> 6;
    if ((tid & 63) == 0) { sm[wave] = m; ss[wave] = s; sbi[wave] = bi; }
    __syncthreads();

    if (tid == 0) {
#pragma unroll
        for (int w = 1; w < THREADS / 64; ++w) {
            float m2 = sm[w], s2 = ss[w];
            int bi2 = sbi[w];
            bool take = (m2 > m) || (m2 == m && bi2 < bi);
            float nm = fmaxf(m, m2);
            s = s * __expf(m - nm) + s2 * __expf(m2 - nm);
            if (take) bi = bi2;
            m = nm;
        }
        const int t = target[row];
        const float xt = rp[t];                 // row just streamed; L2-hot
        const float nll = logf(s) + m - xt;     // -log_softmax[target]
        nll_out[row] = (t != IGNORE_IDX) ? nll : 0.0f;
        am_out[row] = bi;
    }
}

// ---------------------------------------------------------------------------
// Kernel 2: single block. CE mean + first-EOS / NEXT_LINE-count logic + final.
// ---------------------------------------------------------------------------
__device__ __forceinline__ int block_first_stop(const int* __restrict__ ids,
                                                int S, int tid, int* si)
{
    int lmin = INT_MAX;
    for (int i = tid; i < S; i += THREADS)
        if (ids[i] == EOS_ID) { lmin = i; break; }   // strided: first hit is min for this thread
    si[tid] = lmin;
    __syncthreads();
    for (int off = THREADS / 2; off > 0; off >>= 1) {
        if (tid < off) si[tid] = min(si[tid], si[tid + off]);
        __syncthreads();
    }
    int first = min(si[0], S - 1);
    __syncthreads();
    return first;
}

__device__ __forceinline__ int block_count_nl(const int* __restrict__ ids,
                                              int first, int tid, int* si)
{
    int lc = 0;
    for (int i = tid; i <= first; i += THREADS)
        lc += (ids[i] == NEXT_LINE_ID) ? 1 : 0;
    si[tid] = lc;
    __syncthreads();
    for (int off = THREADS / 2; off > 0; off >>= 1) {
        if (tid < off) si[tid] += si[tid + off];
        __syncthreads();
    }
    int c = si[0];
    __syncthreads();
    return c;
}

__global__ __launch_bounds__(THREADS) void finalize_kernel(
    const float* __restrict__ nll, const int* __restrict__ am,
    const int* __restrict__ target, float* __restrict__ out, int B, int S)
{
    __shared__ float sf[THREADS];
    __shared__ int si[THREADS];
    const int tid = threadIdx.x;
    const int BS = B * S;

    // CE numerator + valid count (deterministic fixed-order tree)
    float ces = 0.0f;
    int vc = 0;
    for (int i = tid; i < BS; i += THREADS) {
        ces += nll[i];
        vc += (target[i] != IGNORE_IDX) ? 1 : 0;
    }
    sf[tid] = ces; si[tid] = vc;
    __syncthreads();
    for (int off = THREADS / 2; off > 0; off >>= 1) {
        if (tid < off) { sf[tid] += sf[tid + off]; si[tid] += si[tid + off]; }
        __syncthreads();
    }
    const float ce_total = sf[0];
    const int vtot = si[0];
    __syncthreads();

    int sum_len = 0, sum_cnt = 0;
    for (int b = 0; b < B; ++b) {
        const int* amb = am + b * S;
        const int* tgb = target + b * S;
        int fp = block_first_stop(amb, S, tid, si);
        int cp = block_count_nl(amb, fp, tid, si);
        int ft = block_first_stop(tgb, S, tid, si);
        int ct = block_count_nl(tgb, ft, tid, si);
        sum_len += abs(fp - ft);
        sum_cnt += abs(cp - ct);
    }

    if (tid == 0) {
        float ce = ce_total / fmaxf((float)vtot, 1.0f);
        float len_loss = (float)sum_len / (float)B;
        float line_loss = (float)sum_cnt / (float)B;
        out[0] = 0.98f * ce + 0.01f * len_loss + 0.01f * line_loss;
    }
}

extern "C" void kernel_launch(void* const* d_in, const int* in_sizes, int n_in,
                              void* d_out, int out_size, void* d_ws, size_t ws_size,
                              hipStream_t stream)
{
    const float* pred = (const float*)d_in[0];
    const int* target = (const int*)d_in[1];
    float* out = (float*)d_out;

    const int rows = in_sizes[1];            // B*S = 8192
    const int V = (int)((long long)in_sizes[0] / rows);  // 32000
    const int B = 4;
    const int S = rows / B;                  // 2048

    float* nll = (float*)d_ws;
    int* am = (int*)(nll + rows);

    row_pass_kernel<<<rows, THREADS, 0, stream>>>(pred, target, nll, am, V);
    finalize_kernel<<<1, THREADS, 0, stream>>>(nll, am, target, out, B, S);
}

// Round 2
// 194.244 us; speedup vs baseline: 1.1540x; 1.1540x over previous
//
#include <hip/hip_runtime.h>
#include <cfloat>
#include <climits>

#define EOS_ID 1
#define NEXT_LINE_ID 2
#define IGNORE_IDX 0

constexpr int THREADS = 256;
constexpr float LOG2E = 1.4426950408889634f;

typedef float vf4 __attribute__((ext_vector_type(4)));

// ---------------------------------------------------------------------------
// Kernel 1: one block per (b,s) row of V logits.
// Chunked online softmax: 16 elements/iter via 4 coalesced float4 loads,
// chunk-max tree + single deferred rescale (17 exps / 16 elems, all parallel),
// argmax with first-index tie-break. Deterministic reduction order.
// ---------------------------------------------------------------------------
__global__ __launch_bounds__(THREADS) void row_pass_kernel(
    const float* __restrict__ pred, const int* __restrict__ target,
    float* __restrict__ nll_out, int* __restrict__ am_out, int V)
{
    const int row = blockIdx.x;
    const float* rp = pred + (size_t)row * (size_t)V;
    const int tid = threadIdx.x;
    const int V4 = V >> 2;          // float4 count (8000)
    const int SEG = V4 >> 2;        // float4 per segment (2000), 4 segments
    const int SEG4 = SEG << 2;      // elements per segment (8000)

    const int t = target[row];
    float xt = 0.0f;
    if (tid == 0) xt = rp[t];       // issue early; consumed after the loop

    const vf4* rp4 = (const vf4*)rp;

    float m = -FLT_MAX;
    float s = 0.0f;
    int bi = 0;

    for (int i = tid; i < SEG; i += THREADS) {
        vf4 v0 = __builtin_nontemporal_load(rp4 + i);
        vf4 v1 = __builtin_nontemporal_load(rp4 + i + SEG);
        vf4 v2 = __builtin_nontemporal_load(rp4 + i + 2 * SEG);
        vf4 v3 = __builtin_nontemporal_load(rp4 + i + 3 * SEG);
        float x[16];
#pragma unroll
        for (int c = 0; c < 4; ++c) {
            x[c] = v0[c]; x[4 + c] = v1[c]; x[8 + c] = v2[c]; x[12 + c] = v3[c];
        }
        // chunk max (tree, ILP)
        float m8[8];
#pragma unroll
        for (int j = 0; j < 8; ++j) m8[j] = fmaxf(x[2 * j], x[2 * j + 1]);
        float m4[4];
#pragma unroll
        for (int j = 0; j < 4; ++j) m4[j] = fmaxf(m8[2 * j], m8[2 * j + 1]);
        float mc = fmaxf(fmaxf(m4[0], m4[1]), fmaxf(m4[2], m4[3]));

        // earliest-index element offset of mc within the chunk.
        // slot j holds element (i<<2) + (j>>2)*SEG4 + (j&3); slot order is
        // increasing global index, so scanning j=14..0 keeps the earliest.
        int off = 3 * SEG4 + 3;
#pragma unroll
        for (int j = 14; j >= 0; --j)
            off = (x[j] == mc) ? ((j >> 2) * SEG4 + (j & 3)) : off;
        if (mc > m) bi = (i << 2) + off;   // strict > keeps earliest across chunks

        // deferred-rescale exp sum (all exps independent)
        float nm = fmaxf(m, mc);
        float nms = -nm * LOG2E;
        float r = exp2f(__builtin_fmaf(m, LOG2E, nms)); // m=-FLT_MAX -> exp2(-inf)=0
#pragma unroll
        for (int j = 0; j < 16; ++j)
            x[j] = exp2f(__builtin_fmaf(x[j], LOG2E, nms));
#pragma unroll
        for (int j = 0; j < 8; ++j) x[j] += x[j + 8];
#pragma unroll
        for (int j = 0; j < 4; ++j) x[j] += x[j + 4];
        float cs = (x[0] + x[1]) + (x[2] + x[3]);
        s = __builtin_fmaf(s, r, cs);
        m = nm;
    }

    // generic scalar tail (empty for V % 16 == 0)
    for (int i = (SEG << 4) + tid; i < V; i += THREADS) {
        float xv = rp[i];
        float nm = fmaxf(m, xv);
        float nms = -nm * LOG2E;
        s = s * exp2f(__builtin_fmaf(m, LOG2E, nms))
          + exp2f(__builtin_fmaf(xv, LOG2E, nms));
        if (xv > m) bi = i;
        m = nm;
    }

    // wave64 reduction
#pragma unroll
    for (int off = 32; off > 0; off >>= 1) {
        float m2 = __shfl_down(m, off);
        float s2 = __shfl_down(s, off);
        int bi2 = __shfl_down(bi, off);
        float nm = fmaxf(m, m2);
        float nms = -nm * LOG2E;
        s = s * exp2f(__builtin_fmaf(m, LOG2E, nms))
          + s2 * exp2f(__builtin_fmaf(m2, LOG2E, nms));
        bool take = (m2 > m) || (m2 == m && bi2 < bi);
        bi = take ? bi2 : bi;
        m = nm;
    }

    __shared__ float sm[THREADS / 64], ss[THREADS / 64];
    __shared__ int sbi[THREADS / 64];
    const int wave = tid >> 6;
    if ((tid & 63) == 0) { sm[wave] = m; ss[wave] = s; sbi[wave] = bi; }
    __syncthreads();

    if (tid == 0) {
#pragma unroll
        for (int w = 1; w < THREADS / 64; ++w) {
            float m2 = sm[w], s2 = ss[w];
            int bi2 = sbi[w];
            float nm = fmaxf(m, m2);
            float nms = -nm * LOG2E;
            s = s * exp2f(__builtin_fmaf(m, LOG2E, nms))
              + s2 * exp2f(__builtin_fmaf(m2, LOG2E, nms));
            bool take = (m2 > m) || (m2 == m && bi2 < bi);
            bi = take ? bi2 : bi;
            m = nm;
        }
        const float nll = logf(s) + m - xt;   // -log_softmax[target]
        nll_out[row] = (t != IGNORE_IDX) ? nll : 0.0f;
        am_out[row] = bi;
    }
}

// ---------------------------------------------------------------------------
// Kernel 2: single block. CE mean (block tree) + per-wave first-EOS /
// NEXT_LINE-count scans (one wave per batch row, shfl-only) + final scalar.
// ---------------------------------------------------------------------------
__device__ __forceinline__ int wave_first_stop(const int* __restrict__ ids,
                                               int S, int lane)
{
    int lmin = INT_MAX;
    for (int i = lane; i < S; i += 64)
        if (ids[i] == EOS_ID) { lmin = i; break; }  // strided: first hit = lane min
#pragma unroll
    for (int off = 32; off > 0; off >>= 1)
        lmin = min(lmin, __shfl_down(lmin, off));
    lmin = __shfl(lmin, 0);
    return min(lmin, S - 1);
}

__device__ __forceinline__ int wave_count_nl(const int* __restrict__ ids,
                                             int first, int lane)
{
    int c = 0;
    for (int i = lane; i <= first; i += 64)
        c += (ids[i] == NEXT_LINE_ID) ? 1 : 0;
#pragma unroll
    for (int off = 32; off > 0; off >>= 1)
        c += __shfl_down(c, off);
    return __shfl(c, 0);
}

__global__ __launch_bounds__(THREADS) void finalize_kernel(
    const float* __restrict__ nll, const int* __restrict__ am,
    const int* __restrict__ target, float* __restrict__ out, int B, int S)
{
    __shared__ float sf[THREADS];
    __shared__ int si[THREADS];
    __shared__ int slen[THREADS / 64], scnt[THREADS / 64];
    const int tid = threadIdx.x;
    const int BS = B * S;

    // CE numerator + valid count (deterministic fixed-order tree)
    float ces = 0.0f;
    int vc = 0;
    for (int i = tid; i < BS; i += THREADS) {
        ces += nll[i];
        vc += (target[i] != IGNORE_IDX) ? 1 : 0;
    }
    sf[tid] = ces; si[tid] = vc;
    __syncthreads();
    for (int off = THREADS / 2; off > 0; off >>= 1) {
        if (tid < off) { sf[tid] += sf[tid + off]; si[tid] += si[tid + off]; }
        __syncthreads();
    }
    const float ce_total = sf[0];
    const int vtot = si[0];

    // one wave per batch row, shfl-only (no block barriers inside)
    const int wave = tid >> 6, lane = tid & 63;
    int lsum = 0, csum = 0;
    for (int b = wave; b < B; b += (THREADS / 64)) {
        const int* amb = am + b * S;
        const int* tgb = target + b * S;
        int fp = wave_first_stop(amb, S, lane);
        int cp = wave_count_nl(amb, fp, lane);
        int ft = wave_first_stop(tgb, S, lane);
        int ct = wave_count_nl(tgb, ft, lane);
        lsum += abs(fp - ft);
        csum += abs(cp - ct);
    }
    if (lane == 0) { slen[wave] = lsum; scnt[wave] = csum; }
    __syncthreads();

    if (tid == 0) {
        int SL = 0, SC = 0;
#pragma unroll
        for (int w = 0; w < THREADS / 64; ++w) { SL += slen[w]; SC += scnt[w]; }
        float ce = ce_total / fmaxf((float)vtot, 1.0f);
        out[0] = 0.98f * ce + 0.01f * ((float)SL / (float)B)
                            + 0.01f * ((float)SC / (float)B);
    }
}

extern "C" void kernel_launch(void* const* d_in, const int* in_sizes, int n_in,
                              void* d_out, int out_size, void* d_ws, size_t ws_size,
                              hipStream_t stream)
{
    const float* pred = (const float*)d_in[0];
    const int* target = (const int*)d_in[1];
    float* out = (float*)d_out;

    const int rows = in_sizes[1];                         // B*S = 8192
    const int V = (int)((long long)in_sizes[0] / rows);   // 32000
    const int B = 4;
    const int S = rows / B;                               // 2048

    float* nll = (float*)d_ws;
    int* am = (int*)(nll + rows);

    row_pass_kernel<<<rows, THREADS, 0, stream>>>(pred, target, nll, am, V);
    finalize_kernel<<<1, THREADS, 0, stream>>>(nll, am, target, out, B, S);
}

// Round 3
// 169.764 us; speedup vs baseline: 1.3204x; 1.1442x over previous
//
#include <hip/hip_runtime.h>
#include <cfloat>
#include <climits>

#define EOS_ID 1
#define NEXT_LINE_ID 2
#define IGNORE_IDX 0

constexpr int THREADS = 256;
constexpr int FTHREADS = 1024;
constexpr float LOG2E = 1.4426950408889634f;

typedef float vf4 __attribute__((ext_vector_type(4)));

// ---------------------------------------------------------------------------
// Kernel 1: one block per (b,s) row of V logits.
// Chunked online softmax: 16 elements/iter via 4 coalesced float4 loads,
// chunk-max tree + single deferred rescale (17 exps / 16 elems, all parallel),
// argmax with first-index tie-break. Deterministic reduction order.
// ---------------------------------------------------------------------------
__global__ __launch_bounds__(THREADS) void row_pass_kernel(
    const float* __restrict__ pred, const int* __restrict__ target,
    float* __restrict__ nll_out, int* __restrict__ am_out, int V)
{
    const int row = blockIdx.x;
    const float* rp = pred + (size_t)row * (size_t)V;
    const int tid = threadIdx.x;
    const int V4 = V >> 2;          // float4 count (8000)
    const int SEG = V4 >> 2;        // float4 per segment (2000), 4 segments
    const int SEG4 = SEG << 2;      // elements per segment (8000)

    const int t = target[row];
    float xt = 0.0f;
    if (tid == 0) xt = rp[t];       // issue early; consumed after the loop

    const vf4* rp4 = (const vf4*)rp;

    float m = -FLT_MAX;
    float s = 0.0f;
    int bi = 0;

    for (int i = tid; i < SEG; i += THREADS) {
        vf4 v0 = __builtin_nontemporal_load(rp4 + i);
        vf4 v1 = __builtin_nontemporal_load(rp4 + i + SEG);
        vf4 v2 = __builtin_nontemporal_load(rp4 + i + 2 * SEG);
        vf4 v3 = __builtin_nontemporal_load(rp4 + i + 3 * SEG);
        float x[16];
#pragma unroll
        for (int c = 0; c < 4; ++c) {
            x[c] = v0[c]; x[4 + c] = v1[c]; x[8 + c] = v2[c]; x[12 + c] = v3[c];
        }
        // chunk max (tree, ILP)
        float m8[8];
#pragma unroll
        for (int j = 0; j < 8; ++j) m8[j] = fmaxf(x[2 * j], x[2 * j + 1]);
        float m4[4];
#pragma unroll
        for (int j = 0; j < 4; ++j) m4[j] = fmaxf(m8[2 * j], m8[2 * j + 1]);
        float mc = fmaxf(fmaxf(m4[0], m4[1]), fmaxf(m4[2], m4[3]));

        // earliest-index element offset of mc within the chunk.
        // slot j holds element (i<<2) + (j>>2)*SEG4 + (j&3); slot order is
        // increasing global index, so scanning j=14..0 keeps the earliest.
        int off = 3 * SEG4 + 3;
#pragma unroll
        for (int j = 14; j >= 0; --j)
            off = (x[j] == mc) ? ((j >> 2) * SEG4 + (j & 3)) : off;
        if (mc > m) bi = (i << 2) + off;   // strict > keeps earliest across chunks

        // deferred-rescale exp sum (all exps independent)
        float nm = fmaxf(m, mc);
        float nms = -nm * LOG2E;
        float r = exp2f(__builtin_fmaf(m, LOG2E, nms)); // m=-FLT_MAX -> exp2(-inf)=0
#pragma unroll
        for (int j = 0; j < 16; ++j)
            x[j] = exp2f(__builtin_fmaf(x[j], LOG2E, nms));
#pragma unroll
        for (int j = 0; j < 8; ++j) x[j] += x[j + 8];
#pragma unroll
        for (int j = 0; j < 4; ++j) x[j] += x[j + 4];
        float cs = (x[0] + x[1]) + (x[2] + x[3]);
        s = __builtin_fmaf(s, r, cs);
        m = nm;
    }

    // generic scalar tail (empty for V % 16 == 0)
    for (int i = (SEG << 4) + tid; i < V; i += THREADS) {
        float xv = rp[i];
        float nm = fmaxf(m, xv);
        float nms = -nm * LOG2E;
        s = s * exp2f(__builtin_fmaf(m, LOG2E, nms))
          + exp2f(__builtin_fmaf(xv, LOG2E, nms));
        if (xv > m) bi = i;
        m = nm;
    }

    // wave64 reduction
#pragma unroll
    for (int off = 32; off > 0; off >>= 1) {
        float m2 = __shfl_down(m, off);
        float s2 = __shfl_down(s, off);
        int bi2 = __shfl_down(bi, off);
        float nm = fmaxf(m, m2);
        float nms = -nm * LOG2E;
        s = s * exp2f(__builtin_fmaf(m, LOG2E, nms))
          + s2 * exp2f(__builtin_fmaf(m2, LOG2E, nms));
        bool take = (m2 > m) || (m2 == m && bi2 < bi);
        bi = take ? bi2 : bi;
        m = nm;
    }

    __shared__ float sm[THREADS / 64], ss[THREADS / 64];
    __shared__ int sbi[THREADS / 64];
    const int wave = tid >> 6;
    if ((tid & 63) == 0) { sm[wave] = m; ss[wave] = s; sbi[wave] = bi; }
    __syncthreads();

    if (tid == 0) {
#pragma unroll
        for (int w = 1; w < THREADS / 64; ++w) {
            float m2 = sm[w], s2 = ss[w];
            int bi2 = sbi[w];
            float nm = fmaxf(m, m2);
            float nms = -nm * LOG2E;
            s = s * exp2f(__builtin_fmaf(m, LOG2E, nms))
              + s2 * exp2f(__builtin_fmaf(m2, LOG2E, nms));
            bool take = (m2 > m) || (m2 == m && bi2 < bi);
            bi = take ? bi2 : bi;
            m = nm;
        }
        const float nll = logf(s) + m - xt;   // -log_softmax[target]
        nll_out[row] = (t != IGNORE_IDX) ? nll : 0.0f;
        am_out[row] = bi;
    }
}

// ---------------------------------------------------------------------------
// Kernel 2: single 1024-thread block, fully vectorized.
//  - CE sum + valid count: float4/int4 loads, 2 iters/thread, wave shfl reduce.
//  - Scans: 8 wave-tasks (4 rows x {argmax,target}), int4 loads, 8 iters/lane.
//  - One barrier, LDS combine, thread 0 writes the scalar.
// ---------------------------------------------------------------------------
__global__ __launch_bounds__(FTHREADS) void finalize_kernel(
    const float* __restrict__ nll, const int* __restrict__ am,
    const int* __restrict__ target, float* __restrict__ out, int B, int S)
{
    __shared__ float sf[FTHREADS / 64];
    __shared__ int sv[FTHREADS / 64];
    __shared__ int sfirst[8], scount[8];

    const int tid = threadIdx.x;
    const int lane = tid & 63;
    const int wave = tid >> 6;
    const int BS = B * S;

    // ---- CE numerator + valid count (vectorized, deterministic order) ----
    float ces = 0.0f;
    int vc = 0;
    const float4* nll4 = (const float4*)nll;
    const int4* tg4 = (const int4*)target;
    const int NV = BS >> 2;
    for (int i = tid; i < NV; i += FTHREADS) {
        float4 v = nll4[i];
        ces += (v.x + v.y) + (v.z + v.w);
        int4 tv = tg4[i];
        vc += (tv.x != IGNORE_IDX) + (tv.y != IGNORE_IDX)
            + (tv.z != IGNORE_IDX) + (tv.w != IGNORE_IDX);
    }
#pragma unroll
    for (int off = 32; off > 0; off >>= 1) {
        ces += __shfl_down(ces, off);
        vc += __shfl_down(vc, off);
    }
    if (lane == 0) { sf[wave] = ces; sv[wave] = vc; }

    // ---- scans: wave w handles row w>>1, array (w&1 ? target : am) ----
    if (wave < 2 * B) {
        const int row = wave >> 1;
        const int* ids = (wave & 1) ? (target + row * S) : (am + row * S);
        const int4* id4 = (const int4*)ids;
        const int S4 = S >> 2;

        int lmin = INT_MAX;
        for (int i = lane; i < S4; i += 64) {
            int4 v = id4[i];
            const int base = i << 2;
            int idx = INT_MAX;
            if (v.w == EOS_ID) idx = base + 3;
            if (v.z == EOS_ID) idx = base + 2;
            if (v.y == EOS_ID) idx = base + 1;
            if (v.x == EOS_ID) idx = base;
            lmin = min(lmin, idx);
        }
#pragma unroll
        for (int off = 32; off > 0; off >>= 1)
            lmin = min(lmin, __shfl_down(lmin, off));
        lmin = __shfl(lmin, 0);
        const int first = min(lmin, S - 1);

        int c = 0;
        for (int i = lane; i < S4; i += 64) {
            int4 v = id4[i];                    // L1-hot second pass
            const int base = i << 2;
            c += (v.x == NEXT_LINE_ID && base <= first);
            c += (v.y == NEXT_LINE_ID && base + 1 <= first);
            c += (v.z == NEXT_LINE_ID && base + 2 <= first);
            c += (v.w == NEXT_LINE_ID && base + 3 <= first);
        }
#pragma unroll
        for (int off = 32; off > 0; off >>= 1)
            c += __shfl_down(c, off);
        if (lane == 0) { sfirst[wave] = first; scount[wave] = c; }
    }
    __syncthreads();

    if (tid == 0) {
        float ce_total = 0.0f;
        int vtot = 0;
#pragma unroll
        for (int w = 0; w < FTHREADS / 64; ++w) { ce_total += sf[w]; vtot += sv[w]; }
        int SL = 0, SC = 0;
#pragma unroll
        for (int b = 0; b < 4; ++b) {
            SL += abs(sfirst[2 * b] - sfirst[2 * b + 1]);
            SC += abs(scount[2 * b] - scount[2 * b + 1]);
        }
        float ce = ce_total / fmaxf((float)vtot, 1.0f);
        out[0] = 0.98f * ce + 0.01f * ((float)SL / (float)B)
                            + 0.01f * ((float)SC / (float)B);
    }
}

extern "C" void kernel_launch(void* const* d_in, const int* in_sizes, int n_in,
                              void* d_out, int out_size, void* d_ws, size_t ws_size,
                              hipStream_t stream)
{
    const float* pred = (const float*)d_in[0];
    const int* target = (const int*)d_in[1];
    float* out = (float*)d_out;

    const int rows = in_sizes[1];                         // B*S = 8192
    const int V = (int)((long long)in_sizes[0] / rows);   // 32000
    const int B = 4;
    const int S = rows / B;                               // 2048

    float* nll = (float*)d_ws;
    int* am = (int*)(nll + rows);

    row_pass_kernel<<<rows, THREADS, 0, stream>>>(pred, target, nll, am, V);
    finalize_kernel<<<1, FTHREADS, 0, stream>>>(nll, am, target, out, B, S);
}